// Round 5
// baseline (410.647 us; speedup 1.0000x reference)
//
#include <hip/hip_runtime.h>
#include <hip/hip_bf16.h>

#define SEQN 4096
#define HD 64
#define CCH 512
#define NH 8
#define SC 4            // s-split chunks
#define CHUNK (SEQN / SC)

typedef __attribute__((ext_vector_type(8))) short short8;   // 8 bf16 (4 VGPRs)
typedef __attribute__((ext_vector_type(4))) float f32x4;    // 4 fp32 acc

#define AS1 __attribute__((address_space(1)))
#define AS3 __attribute__((address_space(3)))

#if __has_builtin(__builtin_amdgcn_exp2f)
#define EXP2(x) __builtin_amdgcn_exp2f(x)
#else
#define EXP2(x) exp2f(x)
#endif

// 0.125 * log2(e): fold the attention scale AND exp->exp2 conversion into Q
#define QSCALE 0.18033688011112042f

static __device__ __forceinline__ unsigned short f2bf(float f) {
    __hip_bfloat16 h = __float2bfloat16(f);
    return *(unsigned short*)&h;
}
static __device__ __forceinline__ float bf2f(unsigned short u) {
    unsigned int v = ((unsigned int)u) << 16;
    return *(float*)&v;
}
static __device__ __forceinline__ unsigned int fbits(float f) { return *(unsigned int*)&f; }
static __device__ __forceinline__ float hi_f(unsigned int v) {
    unsigned int t = v & 0xFFFF0000u; return *(float*)&t;
}
static __device__ __forceinline__ float lo_f(unsigned int v) {
    unsigned int t = v << 16; return *(float*)&t;
}
// truncating pack of two f32 -> two bf16 in one dword (lo, hi)
static __device__ __forceinline__ unsigned int pkbf(float lo, float hi) {
    return (fbits(hi) & 0xFFFF0000u) | (fbits(lo) >> 16);
}
static __device__ __forceinline__ void load_lds_16(const unsigned short* g, unsigned short* l) {
    __builtin_amdgcn_global_load_lds((const AS1 void*)g, (AS3 void*)l, 16, 0, 0);
}

// ---------------- GroupNorm partial stats: 256 blocks, 8 slices per group
__global__ __launch_bounds__(256) void gn_stats(const float* __restrict__ x,
                                                float2* __restrict__ partials) {
    const int b = blockIdx.x;
    const int g = b >> 3;
    const int slice = b & 7;
    const float* xs = x + (size_t)g * 65536 + slice * 8192;
    const int tid = threadIdx.x;
    float s = 0.f, ss = 0.f;
    for (int i = tid; i < 2048; i += 256) {
        float4 v = ((const float4*)xs)[i];
        s  += v.x + v.y + v.z + v.w;
        ss += v.x * v.x + v.y * v.y + v.z * v.z + v.w * v.w;
    }
    for (int off = 32; off; off >>= 1) {
        s  += __shfl_xor(s, off);
        ss += __shfl_xor(ss, off);
    }
    __shared__ float red[8];
    const int wave = tid >> 6;
    const int lane = tid & 63;
    if (lane == 0) { red[wave] = s; red[4 + wave] = ss; }
    __syncthreads();
    if (tid == 0) {
        partials[b] = make_float2(red[0] + red[1] + red[2] + red[3],
                                  red[4] + red[5] + red[6] + red[7]);
    }
}

// ---------------- GroupNorm finalize + apply + transpose: x[c][t] -> xnT[t][c] bf16
__global__ __launch_bounds__(256) void gn_norm_t(const float* __restrict__ x,
                                                 const float2* __restrict__ partials,
                                                 const float* __restrict__ w,
                                                 const float* __restrict__ b,
                                                 unsigned short* __restrict__ xnT) {
    __shared__ float tile[64][65];
    __shared__ float gmean[4], grstd[4];
    const int t0 = blockIdx.x * 64;
    const int c0 = blockIdx.y * 64;
    const int tid = threadIdx.x;
    if (tid < 4) {
        int g = (c0 >> 4) + tid;
        float s = 0.f, ss = 0.f;
#pragma unroll
        for (int i = 0; i < 8; i++) {
            float2 p = partials[g * 8 + i];
            s += p.x; ss += p.y;
        }
        float mean = s * (1.f / 65536.f);
        float var  = ss * (1.f / 65536.f) - mean * mean;
        gmean[tid] = mean;
        grstd[tid] = rsqrtf(var + 1e-5f);
    }
    __syncthreads();
    for (int e = tid; e < 1024; e += 256) {
        int r  = e >> 4;
        int t4 = (e & 15) << 2;
        int c = c0 + r;
        float rstd = grstd[r >> 4];
        float sc = w[c] * rstd;
        float sh = b[c] - gmean[r >> 4] * sc;
        float4 v = *(const float4*)(x + (size_t)c * SEQN + t0 + t4);
        tile[r][t4 + 0] = v.x * sc + sh;
        tile[r][t4 + 1] = v.y * sc + sh;
        tile[r][t4 + 2] = v.z * sc + sh;
        tile[r][t4 + 3] = v.w * sc + sh;
    }
    __syncthreads();
    for (int e = tid; e < 1024; e += 256) {
        int t  = e >> 4;
        int c4 = (e & 15) << 2;
        ushort4 o;
        o.x = f2bf(tile[c4 + 0][t]);
        o.y = f2bf(tile[c4 + 1][t]);
        o.z = f2bf(tile[c4 + 2][t]);
        o.w = f2bf(tile[c4 + 3][t]);
        *(ushort4*)(xnT + (size_t)(t0 + t) * CCH + c0 + c4) = o;
    }
}

// ---------------- both weight matrices fp32 -> bf16, one dispatch
__global__ __launch_bounds__(256) void cvt_w(const float* __restrict__ qkv_w,
                                             const float* __restrict__ proj_w,
                                             unsigned short* __restrict__ wq,
                                             unsigned short* __restrict__ wp) {
    const int i = blockIdx.x * 256 + threadIdx.x;
    const int NQ = 3 * CCH * CCH / 4;
    float4 f;
    unsigned short* d;
    if (i < NQ) { f = ((const float4*)qkv_w)[i]; d = wq + (size_t)i * 4; }
    else        { f = ((const float4*)proj_w)[i - NQ]; d = wp + (size_t)(i - NQ) * 4; }
    ushort4 o;
    o.x = f2bf(f.x); o.y = f2bf(f.y); o.z = f2bf(f.z); o.w = f2bf(f.w);
    *(ushort4*)d = o;
}

// ---------------- QKV GEMM: 128x128 tile, BK=64, LDS-staged (m97 style).
// A = Wb [1536][512], B = xnT [4096][512]. Fused epilogue -> qt/kt [h][t][d]
// (Q scaled by QSCALE) and vv [c][t] bf16.
__global__ __launch_bounds__(256) void gemm_qkv(const unsigned short* __restrict__ Wb,
                                                const unsigned short* __restrict__ xnT,
                                                const float* __restrict__ bias,
                                                unsigned short* __restrict__ qt,
                                                unsigned short* __restrict__ kt,
                                                unsigned short* __restrict__ vv) {
    __shared__ __align__(16) unsigned short Asm[128 * 64];
    __shared__ __align__(16) unsigned short Bsm[128 * 64];
    const int tid = threadIdx.x;
    const int wave = tid >> 6;
    const int lane = tid & 63;
    const int quad = lane >> 4;
    const int l15  = lane & 15;
    const int wm = wave >> 1, wn = wave & 1;
    const int nb = blockIdx.x, mb = blockIdx.y;
    const int sl = lane >> 3, slot = lane & 7;
    const int scol = (slot ^ sl) * 8;

    f32x4 acc[4][4];
#pragma unroll
    for (int mt = 0; mt < 4; mt++)
#pragma unroll
        for (int nt = 0; nt < 4; nt++) acc[mt][nt] = (f32x4){0.f, 0.f, 0.f, 0.f};

    for (int kb = 0; kb < CCH; kb += 64) {
        __syncthreads();
#pragma unroll
        for (int i = 0; i < 4; i++) {
            const int c = wave * 4 + i;
            const int row = c * 8 + sl;
            load_lds_16(Wb  + (size_t)(mb * 128 + row) * CCH + kb + scol, &Asm[c * 512]);
            load_lds_16(xnT + (size_t)(nb * 128 + row) * CCH + kb + scol, &Bsm[c * 512]);
        }
        __syncthreads();
#pragma unroll
        for (int kk = 0; kk < 2; kk++) {
            const int so = ((kk * 4 + quad) ^ (l15 & 7)) << 3;
            short8 a[4], b[4];
#pragma unroll
            for (int mt = 0; mt < 4; mt++)
                a[mt] = *(const short8*)(Asm + (wm * 64 + mt * 16 + l15) * 64 + so);
#pragma unroll
            for (int nt = 0; nt < 4; nt++)
                b[nt] = *(const short8*)(Bsm + (wn * 64 + nt * 16 + l15) * 64 + so);
#pragma unroll
            for (int mt = 0; mt < 4; mt++)
#pragma unroll
                for (int nt = 0; nt < 4; nt++)
                    acc[mt][nt] = __builtin_amdgcn_mfma_f32_16x16x32_bf16(a[mt], b[nt], acc[mt][nt], 0, 0, 0);
        }
    }

    const int sel = mb >> 2;                 // 0=Q,1=K,2=V (block-uniform)
#pragma unroll
    for (int mt = 0; mt < 4; mt++) {
        const int m0 = mb * 128 + wm * 64 + mt * 16 + quad * 4;
        float bs[4] = {bias[m0], bias[m0 + 1], bias[m0 + 2], bias[m0 + 3]};
        if (sel < 2) {
            unsigned short* dst = sel ? kt : qt;
            const float mul = sel ? 1.0f : QSCALE;
            const int h  = (m0 >> 6) & 7;
            const int d0 = m0 & 63;
#pragma unroll
            for (int nt = 0; nt < 4; nt++) {
                const int t = nb * 128 + wn * 64 + nt * 16 + l15;
                ushort4 o;
                o.x = f2bf((acc[mt][nt][0] + bs[0]) * mul);
                o.y = f2bf((acc[mt][nt][1] + bs[1]) * mul);
                o.z = f2bf((acc[mt][nt][2] + bs[2]) * mul);
                o.w = f2bf((acc[mt][nt][3] + bs[3]) * mul);
                *(ushort4*)(dst + ((size_t)h * SEQN + t) * HD + d0) = o;
            }
        } else {
            const int c0 = m0 - 1024;
#pragma unroll
            for (int nt = 0; nt < 4; nt++) {
                const int t = nb * 128 + wn * 64 + nt * 16 + l15;
#pragma unroll
                for (int reg = 0; reg < 4; reg++)
                    vv[(size_t)(c0 + reg) * SEQN + t] = f2bf(acc[mt][nt][reg] + bs[reg]);
            }
        }
    }
}

// ---------------- proj GEMM: 64x128 tile, BK=64, LDS-staged; +bias+resid fp32 out
__global__ __launch_bounds__(256) void gemm_proj(const unsigned short* __restrict__ Wb,
                                                 const unsigned short* __restrict__ attnoT,
                                                 const float* __restrict__ bias,
                                                 const float* __restrict__ resid,
                                                 float* __restrict__ out) {
    __shared__ __align__(16) unsigned short Asm[64 * 64];
    __shared__ __align__(16) unsigned short Bsm[128 * 64];
    const int tid = threadIdx.x;
    const int wave = tid >> 6;
    const int lane = tid & 63;
    const int quad = lane >> 4;
    const int l15  = lane & 15;
    const int wm = wave >> 1, wn = wave & 1;
    const int nb = blockIdx.x, mb = blockIdx.y;
    const int sl = lane >> 3, slot = lane & 7;
    const int scol = (slot ^ sl) * 8;

    f32x4 acc[2][4];
#pragma unroll
    for (int mt = 0; mt < 2; mt++)
#pragma unroll
        for (int nt = 0; nt < 4; nt++) acc[mt][nt] = (f32x4){0.f, 0.f, 0.f, 0.f};

    for (int kb = 0; kb < CCH; kb += 64) {
        __syncthreads();
#pragma unroll
        for (int i = 0; i < 2; i++) {
            const int c = wave * 2 + i;
            const int row = c * 8 + sl;
            load_lds_16(Wb + (size_t)(mb * 64 + row) * CCH + kb + scol, &Asm[c * 512]);
        }
#pragma unroll
        for (int i = 0; i < 4; i++) {
            const int c = wave * 4 + i;
            const int row = c * 8 + sl;
            load_lds_16(attnoT + (size_t)(nb * 128 + row) * CCH + kb + scol, &Bsm[c * 512]);
        }
        __syncthreads();
#pragma unroll
        for (int kk = 0; kk < 2; kk++) {
            const int so = ((kk * 4 + quad) ^ (l15 & 7)) << 3;
            short8 a[2], b[4];
#pragma unroll
            for (int mt = 0; mt < 2; mt++)
                a[mt] = *(const short8*)(Asm + (wm * 32 + mt * 16 + l15) * 64 + so);
#pragma unroll
            for (int nt = 0; nt < 4; nt++)
                b[nt] = *(const short8*)(Bsm + (wn * 64 + nt * 16 + l15) * 64 + so);
#pragma unroll
            for (int mt = 0; mt < 2; mt++)
#pragma unroll
                for (int nt = 0; nt < 4; nt++)
                    acc[mt][nt] = __builtin_amdgcn_mfma_f32_16x16x32_bf16(a[mt], b[nt], acc[mt][nt], 0, 0, 0);
        }
    }

#pragma unroll
    for (int mt = 0; mt < 2; mt++) {
        const int m0 = mb * 64 + wm * 32 + mt * 16 + quad * 4;
        float bs[4] = {bias[m0], bias[m0 + 1], bias[m0 + 2], bias[m0 + 3]};
#pragma unroll
        for (int nt = 0; nt < 4; nt++) {
            const int n = nb * 128 + wn * 64 + nt * 16 + l15;
#pragma unroll
            for (int reg = 0; reg < 4; reg++) {
                const size_t off = (size_t)(m0 + reg) * SEQN + n;
                out[off] = acc[mt][nt][reg] + bs[reg] + resid[off];
            }
        }
    }
}

// ---------------- Flash attention: s-partitioned waves, static softmax (exp2,
// scale folded into Q), P stays in registers (C-layout == B-layout for K=16,
// emulated via zero-padded 16x16x32). K staged per-wave, V shared; dbuf LDS.
__global__ __launch_bounds__(256) void attn(const unsigned short* __restrict__ qt,
                                            const unsigned short* __restrict__ kt,
                                            const unsigned short* __restrict__ vv,
                                            unsigned short* __restrict__ po,
                                            float2* __restrict__ ml) {
    const int tid  = threadIdx.x;
    const int wave = tid >> 6;
    const int lane = tid & 63;
    const int quad = lane >> 4;
    const int l15  = lane & 15;
    const int h  = blockIdx.z;
    const int cb = blockIdx.y;
    const int tb = blockIdx.x * 64;

    const unsigned short* qh = qt + (size_t)h * SEQN * HD;
    const unsigned short* kh = kt + (size_t)h * SEQN * HD;
    const unsigned short* vh = vv + (size_t)h * HD * SEQN;

    // kv[buf][0..4095] = K tile (64 s-rows x 64 d), [4096..8191] = V tile (64 d-rows x 64 s)
    __shared__ __align__(16) unsigned short kv[2][8192];
    __shared__ float lred[4][64];

    const int sl = lane >> 3, slot = lane & 7;
    const int scol = (slot ^ sl) * 8;

    // Q B-frags persistent: B[k=d][n=t], all 4 n-tiles
    short8 qf[4][2];
#pragma unroll
    for (int nt = 0; nt < 4; nt++) {
        const unsigned short* qp = qh + (size_t)(tb + nt * 16 + l15) * HD + quad * 8;
        qf[nt][0] = *(const short8*)(qp);
        qf[nt][1] = *(const short8*)(qp + 32);
    }

    f32x4 oacc[4][4];   // O^T partial [d-tile][t-tile] over this wave's s
#pragma unroll
    for (int dt = 0; dt < 4; dt++)
#pragma unroll
        for (int nt = 0; nt < 4; nt++) oacc[dt][nt] = (f32x4){0.f, 0.f, 0.f, 0.f};
    float lsum[4] = {0.f, 0.f, 0.f, 0.f};

    const int s_beg = cb * CHUNK;
    const int NIT = CHUNK / 64;

    auto stage = [&](int buf, int s0) {
        // K: wave stages its OWN 16 s-rows
#pragma unroll
        for (int i = 0; i < 2; i++) {
            const int row = wave * 16 + i * 8 + sl;
            load_lds_16(kh + (size_t)(s0 + row) * HD + scol, &kv[buf][(wave * 16 + i * 8) * 64]);
        }
        // V: shared, wave stages chunks 2w, 2w+1 (d-rows)
#pragma unroll
        for (int i = 0; i < 2; i++) {
            const int c = wave * 2 + i;
            const int row = c * 8 + sl;
            load_lds_16(vh + (size_t)row * SEQN + s0 + scol, &kv[buf][4096 + c * 512]);
        }
    };

    stage(0, s_beg);

    union S8U { short8 s; uint4 u; };

    for (int it = 0; it < NIT; it++) {
        const int cur = it & 1;
        __syncthreads();                        // drains cur's staging; WAR for next
        if (it + 1 < NIT) stage(cur ^ 1, s_beg + (it + 1) * 64);

        const unsigned short* ks  = kv[cur];
        const unsigned short* vsb = kv[cur] + 4096;

        // ---- S^T = K·Q^T over this wave's 16 s-rows: A = K[m=s16][k=d64]
        const int krow = wave * 16 + l15;
        short8 ka0 = *(const short8*)(ks + krow * 64 + (((quad    ) ^ (l15 & 7)) << 3));
        short8 ka1 = *(const short8*)(ks + krow * 64 + (((quad + 4) ^ (l15 & 7)) << 3));
        f32x4 sacc[4];
#pragma unroll
        for (int nt = 0; nt < 4; nt++) {
            f32x4 z = (f32x4){0.f, 0.f, 0.f, 0.f};
            z = __builtin_amdgcn_mfma_f32_16x16x32_bf16(ka0, qf[nt][0], z, 0, 0, 0);
            sacc[nt] = __builtin_amdgcn_mfma_f32_16x16x32_bf16(ka1, qf[nt][1], z, 0, 0, 0);
        }

        // ---- static softmax: p = exp2(s'), accumulate per-lane l partials
        S8U pb[4];
#pragma unroll
        for (int nt = 0; nt < 4; nt++) {
            float p0 = EXP2(sacc[nt][0]);
            float p1 = EXP2(sacc[nt][1]);
            float p2 = EXP2(sacc[nt][2]);
            float p3 = EXP2(sacc[nt][3]);
            lsum[nt] += (p0 + p1) + (p2 + p3);
            pb[nt].u.x = pkbf(p0, p1);
            pb[nt].u.y = pkbf(p2, p3);
            pb[nt].u.z = 0; pb[nt].u.w = 0;
        }

        // ---- O^T += V^T·P^T (K=16 via zero-padded 16x16x32)
        // A: V^T[d=dt*16+l15][s = wave*16 + quad*4 + j], j<4; upper half zero
#pragma unroll
        for (int dt = 0; dt < 4; dt++) {
            const int vrow = dt * 16 + l15;
            const unsigned short* vp = vsb + vrow * 64 +
                ((((2 * wave + (quad >> 1)) ^ (l15 & 7)) << 3) + ((quad & 1) << 2));
            uint2 vd = *(const uint2*)vp;
            S8U va;
            va.u.x = vd.x; va.u.y = vd.y; va.u.z = 0; va.u.w = 0;
#pragma unroll
            for (int nt = 0; nt < 4; nt++)
                oacc[dt][nt] = __builtin_amdgcn_mfma_f32_16x16x32_bf16(va.s, pb[nt].s, oacc[dt][nt], 0, 0, 0);
        }
    }

    // ---- cross-wave reduction: all waves publish packed partials, wave w owns d-slice w
    __syncthreads();
    unsigned int* red = (unsigned int*)&kv[0][0];   // 64 tiles x 64 lanes x 2 dwords = 32 KB
#pragma unroll
    for (int dt = 0; dt < 4; dt++)
#pragma unroll
        for (int nt = 0; nt < 4; nt++) {
            const int tix = ((wave * 16 + dt * 4 + nt) << 6) + lane;
            red[tix * 2]     = pkbf(oacc[dt][nt][0], oacc[dt][nt][1]);
            red[tix * 2 + 1] = pkbf(oacc[dt][nt][2], oacc[dt][nt][3]);
        }
#pragma unroll
    for (int nt = 0; nt < 4; nt++) {
        lsum[nt] += __shfl_xor(lsum[nt], 16);
        lsum[nt] += __shfl_xor(lsum[nt], 32);
    }
    if (quad == 0) {
#pragma unroll
        for (int nt = 0; nt < 4; nt++) lred[wave][nt * 16 + l15] = lsum[nt];
    }
    __syncthreads();

#pragma unroll
    for (int nt = 0; nt < 4; nt++) {
        const int t = tb + nt * 16 + l15;
        float lt = lred[0][nt * 16 + l15] + lred[1][nt * 16 + l15] +
                   lred[2][nt * 16 + l15] + lred[3][nt * 16 + l15];
        f32x4 o = oacc[wave][nt];
#pragma unroll
        for (int pw = 0; pw < 4; pw++) {
            if (pw == wave) continue;
            const int tix = ((pw * 16 + wave * 4 + nt) << 6) + lane;
            unsigned int r0 = red[tix * 2], r1 = red[tix * 2 + 1];
            o[0] += lo_f(r0); o[1] += hi_f(r0);
            o[2] += lo_f(r1); o[3] += hi_f(r1);
        }
        const float rl = 1.0f / lt;
        ushort4 ov;
        ov.x = f2bf(o[0] * rl); ov.y = f2bf(o[1] * rl);
        ov.z = f2bf(o[2] * rl); ov.w = f2bf(o[3] * rl);
        *(ushort4*)(po + ((size_t)(cb * NH + h) * SEQN + t) * HD + wave * 16 + quad * 4) = ov;
        if (wave == 0 && quad == 0)
            ml[(size_t)(cb * NH + h) * SEQN + t] = make_float2(0.f, lt);
    }
}

// ---------------- merge s-chunks -> attnoT [t][c] bf16
__global__ __launch_bounds__(256) void attn_merge(const unsigned short* __restrict__ po,
                                                  const float2* __restrict__ ml,
                                                  unsigned short* __restrict__ attnoT) {
    const int idx = blockIdx.x * 256 + threadIdx.x;
    const int t  = idx >> 7;
    const int c4 = (idx & 127) << 2;
    const int h  = c4 >> 6;
    const int d  = c4 & 63;

    float2 mlv[SC];
    float M = -1e30f;
#pragma unroll
    for (int cb = 0; cb < SC; cb++) {
        mlv[cb] = ml[(size_t)(cb * NH + h) * SEQN + t];
        M = fmaxf(M, mlv[cb].x);
    }
    float a0 = 0.f, a1 = 0.f, a2 = 0.f, a3 = 0.f, denom = 0.f;
#pragma unroll
    for (int cb = 0; cb < SC; cb++) {
        float wgt = __expf(mlv[cb].x - M) * mlv[cb].y;
        denom += wgt;
        ushort4 o = *(const ushort4*)(po + ((size_t)(cb * NH + h) * SEQN + t) * HD + d);
        a0 += wgt * bf2f(o.x);
        a1 += wgt * bf2f(o.y);
        a2 += wgt * bf2f(o.z);
        a3 += wgt * bf2f(o.w);
    }
    const float rd = 1.0f / denom;
    ushort4 r;
    r.x = f2bf(a0 * rd); r.y = f2bf(a1 * rd); r.z = f2bf(a2 * rd); r.w = f2bf(a3 * rd);
    *(ushort4*)(attnoT + (size_t)t * CCH + c4) = r;
}

extern "C" void kernel_launch(void* const* d_in, const int* in_sizes, int n_in,
                              void* d_out, int out_size, void* d_ws, size_t ws_size,
                              hipStream_t stream) {
    const float* x      = (const float*)d_in[0];
    const float* gn_w   = (const float*)d_in[1];
    const float* gn_b   = (const float*)d_in[2];
    const float* qkv_w  = (const float*)d_in[3];
    const float* qkv_b  = (const float*)d_in[4];
    const float* proj_w = (const float*)d_in[5];
    const float* proj_b = (const float*)d_in[6];
    float* out = (float*)d_out;

    char* ws = (char*)d_ws;
    float2* partials = (float2*)ws;                                // 2 KB
    unsigned short* xnT   = (unsigned short*)(ws + 2048);          // 4096*512
    unsigned short* wq_bf = xnT + (size_t)SEQN * CCH;              // 1536*512
    unsigned short* wp_bf = wq_bf + (size_t)3 * CCH * CCH;         // 512*512
    unsigned short* qt    = wp_bf + (size_t)CCH * CCH;             // 8*4096*64
    unsigned short* kt    = qt + (size_t)NH * SEQN * HD;
    unsigned short* vv    = kt + (size_t)NH * SEQN * HD;
    unsigned short* po    = vv + (size_t)NH * SEQN * HD;           // SC*8*4096*64
    unsigned short* attnoT = po + (size_t)SC * NH * SEQN * HD;     // 4096*512
    float2* ml = (float2*)(attnoT + (size_t)SEQN * CCH);           // SC*8*4096

    gn_stats<<<256, 256, 0, stream>>>(x, partials);
    gn_norm_t<<<dim3(SEQN / 64, CCH / 64), 256, 0, stream>>>(x, partials, gn_w, gn_b, xnT);
    cvt_w<<<(3 * CCH * CCH + CCH * CCH) / 4 / 256, 256, 0, stream>>>(qkv_w, proj_w, wq_bf, wp_bf);
    gemm_qkv<<<dim3(SEQN / 128, 3 * CCH / 128), 256, 0, stream>>>(wq_bf, xnT, qkv_b, qt, kt, vv);
    attn<<<dim3(SEQN / 64, SC, NH), 256, 0, stream>>>(qt, kt, vv, po, ml);
    attn_merge<<<SEQN * 128 / 256, 256, 0, stream>>>(po, ml, attnoT);
    gemm_proj<<<dim3(SEQN / 128, CCH / 64), 256, 0, stream>>>(wp_bf, attnoT, proj_b, x, out);
}

// Round 6
// 197.044 us; speedup vs baseline: 2.0840x; 2.0840x over previous
//
#include <hip/hip_runtime.h>
#include <hip/hip_bf16.h>

#define SEQN 4096
#define HD 64
#define CCH 512
#define NH 8
#define SC 4            // s-split chunks
#define CHUNK (SEQN / SC)

typedef __attribute__((ext_vector_type(8))) short short8;   // 8 bf16 (4 VGPRs)
typedef __attribute__((ext_vector_type(4))) float f32x4;    // 4 fp32 acc

#define AS1 __attribute__((address_space(1)))
#define AS3 __attribute__((address_space(3)))

#if __has_builtin(__builtin_amdgcn_exp2f)
#define EXP2(x) __builtin_amdgcn_exp2f(x)
#else
#define EXP2(x) exp2f(x)
#endif

// 0.125 * log2(e): fold attention scale AND exp->exp2 conversion into Q
#define QSCALE 0.18033688011112042f

static __device__ __forceinline__ unsigned short f2bf(float f) {
    __hip_bfloat16 h = __float2bfloat16(f);
    return *(unsigned short*)&h;
}
static __device__ __forceinline__ float bf2f(unsigned short u) {
    unsigned int v = ((unsigned int)u) << 16;
    return *(float*)&v;
}
static __device__ __forceinline__ unsigned int fbits(float f) { return *(unsigned int*)&f; }
static __device__ __forceinline__ float hi_f(unsigned int v) {
    unsigned int t = v & 0xFFFF0000u; return *(float*)&t;
}
static __device__ __forceinline__ float lo_f(unsigned int v) {
    unsigned int t = v << 16; return *(float*)&t;
}
// truncating pack of two f32 -> two bf16 in one dword (lo, hi)
static __device__ __forceinline__ unsigned int pkbf(float lo, float hi) {
    return (fbits(hi) & 0xFFFF0000u) | (fbits(lo) >> 16);
}
// half-K fragment: 4 bf16 in first two dwords, zeros above (NO union: bit_cast
// keeps this in registers — the round-5 union forced scratch allocation)
static __device__ __forceinline__ short8 half_frag(unsigned int a, unsigned int b) {
    uint4 u; u.x = a; u.y = b; u.z = 0u; u.w = 0u;
    return __builtin_bit_cast(short8, u);
}
static __device__ __forceinline__ void load_lds_16(const unsigned short* g, unsigned short* l) {
    __builtin_amdgcn_global_load_lds((const AS1 void*)g, (AS3 void*)l, 16, 0, 0);
}

// ---------------- GroupNorm partial stats: 256 blocks, 8 slices per group
__global__ __launch_bounds__(256) void gn_stats(const float* __restrict__ x,
                                                float2* __restrict__ partials) {
    const int b = blockIdx.x;
    const int g = b >> 3;
    const int slice = b & 7;
    const float* xs = x + (size_t)g * 65536 + slice * 8192;
    const int tid = threadIdx.x;
    float s = 0.f, ss = 0.f;
    for (int i = tid; i < 2048; i += 256) {
        float4 v = ((const float4*)xs)[i];
        s  += v.x + v.y + v.z + v.w;
        ss += v.x * v.x + v.y * v.y + v.z * v.z + v.w * v.w;
    }
    for (int off = 32; off; off >>= 1) {
        s  += __shfl_xor(s, off);
        ss += __shfl_xor(ss, off);
    }
    __shared__ float red[8];
    const int wave = tid >> 6;
    const int lane = tid & 63;
    if (lane == 0) { red[wave] = s; red[4 + wave] = ss; }
    __syncthreads();
    if (tid == 0) {
        partials[b] = make_float2(red[0] + red[1] + red[2] + red[3],
                                  red[4] + red[5] + red[6] + red[7]);
    }
}

// ---------------- GroupNorm finalize + apply + transpose: x[c][t] -> xnT[t][c] bf16
__global__ __launch_bounds__(256) void gn_norm_t(const float* __restrict__ x,
                                                 const float2* __restrict__ partials,
                                                 const float* __restrict__ w,
                                                 const float* __restrict__ b,
                                                 unsigned short* __restrict__ xnT) {
    __shared__ float tile[64][65];
    __shared__ float gmean[4], grstd[4];
    const int t0 = blockIdx.x * 64;
    const int c0 = blockIdx.y * 64;
    const int tid = threadIdx.x;
    if (tid < 4) {
        int g = (c0 >> 4) + tid;
        float s = 0.f, ss = 0.f;
#pragma unroll
        for (int i = 0; i < 8; i++) {
            float2 p = partials[g * 8 + i];
            s += p.x; ss += p.y;
        }
        float mean = s * (1.f / 65536.f);
        float var  = ss * (1.f / 65536.f) - mean * mean;
        gmean[tid] = mean;
        grstd[tid] = rsqrtf(var + 1e-5f);
    }
    __syncthreads();
    for (int e = tid; e < 1024; e += 256) {
        int r  = e >> 4;
        int t4 = (e & 15) << 2;
        int c = c0 + r;
        float rstd = grstd[r >> 4];
        float sc = w[c] * rstd;
        float sh = b[c] - gmean[r >> 4] * sc;
        float4 v = *(const float4*)(x + (size_t)c * SEQN + t0 + t4);
        tile[r][t4 + 0] = v.x * sc + sh;
        tile[r][t4 + 1] = v.y * sc + sh;
        tile[r][t4 + 2] = v.z * sc + sh;
        tile[r][t4 + 3] = v.w * sc + sh;
    }
    __syncthreads();
    for (int e = tid; e < 1024; e += 256) {
        int t  = e >> 4;
        int c4 = (e & 15) << 2;
        ushort4 o;
        o.x = f2bf(tile[c4 + 0][t]);
        o.y = f2bf(tile[c4 + 1][t]);
        o.z = f2bf(tile[c4 + 2][t]);
        o.w = f2bf(tile[c4 + 3][t]);
        *(ushort4*)(xnT + (size_t)(t0 + t) * CCH + c0 + c4) = o;
    }
}

// ---------------- both weight matrices fp32 -> bf16, one dispatch
__global__ __launch_bounds__(256) void cvt_w(const float* __restrict__ qkv_w,
                                             const float* __restrict__ proj_w,
                                             unsigned short* __restrict__ wq,
                                             unsigned short* __restrict__ wp) {
    const int i = blockIdx.x * 256 + threadIdx.x;
    const int NQ = 3 * CCH * CCH / 4;
    float4 f;
    unsigned short* d;
    if (i < NQ) { f = ((const float4*)qkv_w)[i]; d = wq + (size_t)i * 4; }
    else        { f = ((const float4*)proj_w)[i - NQ]; d = wp + (size_t)(i - NQ) * 4; }
    ushort4 o;
    o.x = f2bf(f.x); o.y = f2bf(f.y); o.z = f2bf(f.z); o.w = f2bf(f.w);
    *(ushort4*)d = o;
}

// ---------------- QKV GEMM: 128x128 tile, BK=64, LDS-staged (m97 style).
__global__ __launch_bounds__(256) void gemm_qkv(const unsigned short* __restrict__ Wb,
                                                const unsigned short* __restrict__ xnT,
                                                const float* __restrict__ bias,
                                                unsigned short* __restrict__ qt,
                                                unsigned short* __restrict__ kt,
                                                unsigned short* __restrict__ vv) {
    __shared__ __align__(16) unsigned short Asm[128 * 64];
    __shared__ __align__(16) unsigned short Bsm[128 * 64];
    const int tid = threadIdx.x;
    const int wave = tid >> 6;
    const int lane = tid & 63;
    const int quad = lane >> 4;
    const int l15  = lane & 15;
    const int wm = wave >> 1, wn = wave & 1;
    const int nb = blockIdx.x, mb = blockIdx.y;
    const int sl = lane >> 3, slot = lane & 7;
    const int scol = (slot ^ sl) * 8;

    f32x4 acc[4][4];
#pragma unroll
    for (int mt = 0; mt < 4; mt++)
#pragma unroll
        for (int nt = 0; nt < 4; nt++) acc[mt][nt] = (f32x4){0.f, 0.f, 0.f, 0.f};

    for (int kb = 0; kb < CCH; kb += 64) {
        __syncthreads();
#pragma unroll
        for (int i = 0; i < 4; i++) {
            const int c = wave * 4 + i;
            const int row = c * 8 + sl;
            load_lds_16(Wb  + (size_t)(mb * 128 + row) * CCH + kb + scol, &Asm[c * 512]);
            load_lds_16(xnT + (size_t)(nb * 128 + row) * CCH + kb + scol, &Bsm[c * 512]);
        }
        __syncthreads();
#pragma unroll
        for (int kk = 0; kk < 2; kk++) {
            const int so = ((kk * 4 + quad) ^ (l15 & 7)) << 3;
            short8 a[4], b[4];
#pragma unroll
            for (int mt = 0; mt < 4; mt++)
                a[mt] = *(const short8*)(Asm + (wm * 64 + mt * 16 + l15) * 64 + so);
#pragma unroll
            for (int nt = 0; nt < 4; nt++)
                b[nt] = *(const short8*)(Bsm + (wn * 64 + nt * 16 + l15) * 64 + so);
#pragma unroll
            for (int mt = 0; mt < 4; mt++)
#pragma unroll
                for (int nt = 0; nt < 4; nt++)
                    acc[mt][nt] = __builtin_amdgcn_mfma_f32_16x16x32_bf16(a[mt], b[nt], acc[mt][nt], 0, 0, 0);
        }
    }

    const int sel = mb >> 2;                 // 0=Q,1=K,2=V (block-uniform)
#pragma unroll
    for (int mt = 0; mt < 4; mt++) {
        const int m0 = mb * 128 + wm * 64 + mt * 16 + quad * 4;
        float bs[4] = {bias[m0], bias[m0 + 1], bias[m0 + 2], bias[m0 + 3]};
        if (sel < 2) {
            unsigned short* dst = sel ? kt : qt;
            const float mul = sel ? 1.0f : QSCALE;
            const int h  = (m0 >> 6) & 7;
            const int d0 = m0 & 63;
#pragma unroll
            for (int nt = 0; nt < 4; nt++) {
                const int t = nb * 128 + wn * 64 + nt * 16 + l15;
                ushort4 o;
                o.x = f2bf((acc[mt][nt][0] + bs[0]) * mul);
                o.y = f2bf((acc[mt][nt][1] + bs[1]) * mul);
                o.z = f2bf((acc[mt][nt][2] + bs[2]) * mul);
                o.w = f2bf((acc[mt][nt][3] + bs[3]) * mul);
                *(ushort4*)(dst + ((size_t)h * SEQN + t) * HD + d0) = o;
            }
        } else {
            const int c0 = m0 - 1024;
#pragma unroll
            for (int nt = 0; nt < 4; nt++) {
                const int t = nb * 128 + wn * 64 + nt * 16 + l15;
#pragma unroll
                for (int reg = 0; reg < 4; reg++)
                    vv[(size_t)(c0 + reg) * SEQN + t] = f2bf(acc[mt][nt][reg] + bs[reg]);
            }
        }
    }
}

// ---------------- proj GEMM: 64x128 tile, BK=64, LDS-staged; +bias+resid fp32 out
__global__ __launch_bounds__(256) void gemm_proj(const unsigned short* __restrict__ Wb,
                                                 const unsigned short* __restrict__ attnoT,
                                                 const float* __restrict__ bias,
                                                 const float* __restrict__ resid,
                                                 float* __restrict__ out) {
    __shared__ __align__(16) unsigned short Asm[64 * 64];
    __shared__ __align__(16) unsigned short Bsm[128 * 64];
    const int tid = threadIdx.x;
    const int wave = tid >> 6;
    const int lane = tid & 63;
    const int quad = lane >> 4;
    const int l15  = lane & 15;
    const int wm = wave >> 1, wn = wave & 1;
    const int nb = blockIdx.x, mb = blockIdx.y;
    const int sl = lane >> 3, slot = lane & 7;
    const int scol = (slot ^ sl) * 8;

    f32x4 acc[2][4];
#pragma unroll
    for (int mt = 0; mt < 2; mt++)
#pragma unroll
        for (int nt = 0; nt < 4; nt++) acc[mt][nt] = (f32x4){0.f, 0.f, 0.f, 0.f};

    for (int kb = 0; kb < CCH; kb += 64) {
        __syncthreads();
#pragma unroll
        for (int i = 0; i < 2; i++) {
            const int c = wave * 2 + i;
            const int row = c * 8 + sl;
            load_lds_16(Wb + (size_t)(mb * 64 + row) * CCH + kb + scol, &Asm[c * 512]);
        }
#pragma unroll
        for (int i = 0; i < 4; i++) {
            const int c = wave * 4 + i;
            const int row = c * 8 + sl;
            load_lds_16(attnoT + (size_t)(nb * 128 + row) * CCH + kb + scol, &Bsm[c * 512]);
        }
        __syncthreads();
#pragma unroll
        for (int kk = 0; kk < 2; kk++) {
            const int so = ((kk * 4 + quad) ^ (l15 & 7)) << 3;
            short8 a[2], b[4];
#pragma unroll
            for (int mt = 0; mt < 2; mt++)
                a[mt] = *(const short8*)(Asm + (wm * 32 + mt * 16 + l15) * 64 + so);
#pragma unroll
            for (int nt = 0; nt < 4; nt++)
                b[nt] = *(const short8*)(Bsm + (wn * 64 + nt * 16 + l15) * 64 + so);
#pragma unroll
            for (int mt = 0; mt < 2; mt++)
#pragma unroll
                for (int nt = 0; nt < 4; nt++)
                    acc[mt][nt] = __builtin_amdgcn_mfma_f32_16x16x32_bf16(a[mt], b[nt], acc[mt][nt], 0, 0, 0);
        }
    }

#pragma unroll
    for (int mt = 0; mt < 2; mt++) {
        const int m0 = mb * 64 + wm * 32 + mt * 16 + quad * 4;
        float bs[4] = {bias[m0], bias[m0 + 1], bias[m0 + 2], bias[m0 + 3]};
#pragma unroll
        for (int nt = 0; nt < 4; nt++) {
            const int n = nb * 128 + wn * 64 + nt * 16 + l15;
#pragma unroll
            for (int reg = 0; reg < 4; reg++) {
                const size_t off = (size_t)(m0 + reg) * SEQN + n;
                out[off] = acc[mt][nt][reg] + bs[reg] + resid[off];
            }
        }
    }
}

// ---------------- Flash attention: 2x2 wave grid (wave owns 32 s x 32 t).
// Static softmax (exp2, scale in Q), P in registers via zero-padded MFMA,
// dbuf LDS K/V staging, one barrier/iter, cross-wave O/l reduce per chunk.
__global__ __launch_bounds__(256) void attn(const unsigned short* __restrict__ qt,
                                            const unsigned short* __restrict__ kt,
                                            const unsigned short* __restrict__ vv,
                                            unsigned short* __restrict__ po,
                                            float2* __restrict__ ml) {
    const int tid  = threadIdx.x;
    const int wave = tid >> 6;
    const int lane = tid & 63;
    const int quad = lane >> 4;
    const int l15  = lane & 15;
    const int ws = wave >> 1;      // s-half owner
    const int wt = wave & 1;       // t-half owner
    const int h  = blockIdx.z;
    const int cb = blockIdx.y;
    const int tb = blockIdx.x * 64;

    const unsigned short* qh = qt + (size_t)h * SEQN * HD;
    const unsigned short* kh = kt + (size_t)h * SEQN * HD;
    const unsigned short* vh = vv + (size_t)h * HD * SEQN;

    // kv[buf][0..4095] = K tile (64 s-rows x 64 d, swizzled),
    // kv[buf][4096..8191] = V tile (64 d-rows x 64 s, swizzled)
    __shared__ __align__(16) unsigned short kv[2][8192];
    __shared__ float lredm[4][2][16];

    const int sl = lane >> 3, slot = lane & 7;
    const int scol = (slot ^ sl) * 8;

    // Q B-frags persistent: B[k=d][n=t] for this wave's 2 t-tiles
    short8 qf[2][2];
#pragma unroll
    for (int nt = 0; nt < 2; nt++) {
        const unsigned short* qp = qh + (size_t)(tb + wt * 32 + nt * 16 + l15) * HD + quad * 8;
        qf[nt][0] = *(const short8*)(qp);
        qf[nt][1] = *(const short8*)(qp + 32);
    }

    f32x4 oacc[4][2];   // O^T partial [d-tile 0..3][t-tile 0..1] over this wave's s-half
#pragma unroll
    for (int dt = 0; dt < 4; dt++)
#pragma unroll
        for (int nt = 0; nt < 2; nt++) oacc[dt][nt] = (f32x4){0.f, 0.f, 0.f, 0.f};
    float lsum[2] = {0.f, 0.f};

    const int s_beg = cb * CHUNK;
    const int NIT = CHUNK / 64;

    auto stage = [&](int buf, int s0) {
#pragma unroll
        for (int i = 0; i < 2; i++) {
            const int c = wave * 2 + i;          // chunk 0..7 (8 rows each)
            const int row = c * 8 + sl;
            load_lds_16(kh + (size_t)(s0 + row) * HD + scol, &kv[buf][c * 512]);
            load_lds_16(vh + (size_t)row * SEQN + s0 + scol, &kv[buf][4096 + c * 512]);
        }
    };

    stage(0, s_beg);

    for (int it = 0; it < NIT; it++) {
        const int cur = it & 1;
        __syncthreads();                        // drains cur's staging; WAR for next
        if (it + 1 < NIT) stage(cur ^ 1, s_beg + (it + 1) * 64);

        const unsigned short* ks  = kv[cur];
        const unsigned short* vsb = kv[cur] + 4096;

        // ---- S^T = K·Q^T over this wave's 32 s-rows, 32 t-cols
        short8 ka[2][2];
#pragma unroll
        for (int sm = 0; sm < 2; sm++) {
            const unsigned short* kp = ks + (ws * 32 + sm * 16 + l15) * 64;
            ka[sm][0] = *(const short8*)(kp + (((quad    ) ^ (l15 & 7)) << 3));
            ka[sm][1] = *(const short8*)(kp + (((quad + 4) ^ (l15 & 7)) << 3));
        }
        f32x4 sacc[2][2];
#pragma unroll
        for (int sm = 0; sm < 2; sm++)
#pragma unroll
            for (int nt = 0; nt < 2; nt++) {
                f32x4 z = (f32x4){0.f, 0.f, 0.f, 0.f};
                z = __builtin_amdgcn_mfma_f32_16x16x32_bf16(ka[sm][0], qf[nt][0], z, 0, 0, 0);
                sacc[sm][nt] = __builtin_amdgcn_mfma_f32_16x16x32_bf16(ka[sm][1], qf[nt][1], z, 0, 0, 0);
            }

        // ---- static softmax: p = exp2(s'); per-lane l partials (no cross-lane here)
        unsigned int pbw[2][2][2];
#pragma unroll
        for (int sm = 0; sm < 2; sm++)
#pragma unroll
            for (int nt = 0; nt < 2; nt++) {
                float p0 = EXP2(sacc[sm][nt][0]);
                float p1 = EXP2(sacc[sm][nt][1]);
                float p2 = EXP2(sacc[sm][nt][2]);
                float p3 = EXP2(sacc[sm][nt][3]);
                lsum[nt] += (p0 + p1) + (p2 + p3);
                pbw[sm][nt][0] = pkbf(p0, p1);
                pbw[sm][nt][1] = pkbf(p2, p3);
            }

        // ---- O^T += V^T·P^T (zero-padded K=16 MFMAs; s position (quad,j<4)
        //      holds s = ws*32 + sm*16 + quad*4 + j in BOTH operands)
#pragma unroll
        for (int dt = 0; dt < 4; dt++) {
            const int row = dt * 16 + l15;
#pragma unroll
            for (int sm = 0; sm < 2; sm++) {
                const int col8 = ws * 4 + sm * 2 + (quad >> 1);
                const unsigned short* vp = vsb + row * 64 +
                    ((col8 ^ (l15 & 7)) << 3) + ((quad & 1) << 2);
                uint2 vd = *(const uint2*)vp;
                short8 va = half_frag(vd.x, vd.y);
#pragma unroll
                for (int nt = 0; nt < 2; nt++)
                    oacc[dt][nt] = __builtin_amdgcn_mfma_f32_16x16x32_bf16(
                        va, half_frag(pbw[sm][nt][0], pbw[sm][nt][1]), oacc[dt][nt], 0, 0, 0);
            }
        }
    }

    // ---- cross-wave (ws-pair) reduction through LDS (staging buffers are free)
    __syncthreads();
    unsigned int* exg = (unsigned int*)&kv[0][0];   // 4 waves x 2 dt x 2 nt x 64 lanes x 2 dwords = 8 KB
#pragma unroll
    for (int nt = 0; nt < 2; nt++) {
        lsum[nt] += __shfl_xor(lsum[nt], 16);
        lsum[nt] += __shfl_xor(lsum[nt], 32);
    }
    if (quad == 0) {
        lredm[wave][0][l15] = lsum[0];
        lredm[wave][1][l15] = lsum[1];
    }
#pragma unroll
    for (int j = 0; j < 2; j++) {
        const int dt = (ws ^ 1) * 2 + j;      // the d-half I do NOT own
#pragma unroll
        for (int nt = 0; nt < 2; nt++) {
            const int idx = (((wave * 2 + j) * 2 + nt) * 64 + lane) * 2;
            exg[idx]     = pkbf(oacc[dt][nt][0], oacc[dt][nt][1]);
            exg[idx + 1] = pkbf(oacc[dt][nt][2], oacc[dt][nt][3]);
        }
    }
    __syncthreads();
    const int pw = wave ^ 2;                  // partner: other ws, same wt
    float lt[2];
#pragma unroll
    for (int nt = 0; nt < 2; nt++)
        lt[nt] = lredm[wave][nt][l15] + lredm[pw][nt][l15];

#pragma unroll
    for (int j = 0; j < 2; j++) {
        const int dtm = ws * 2 + j;           // my owned d-tiles
#pragma unroll
        for (int nt = 0; nt < 2; nt++) {
            const int idx = (((pw * 2 + j) * 2 + nt) * 64 + lane) * 2;
            unsigned int r0 = exg[idx], r1 = exg[idx + 1];
            f32x4 o = oacc[dtm][nt];
            o[0] += lo_f(r0); o[1] += hi_f(r0);
            o[2] += lo_f(r1); o[3] += hi_f(r1);
            const float rl = 1.0f / lt[nt];
            const int t = tb + wt * 32 + nt * 16 + l15;
            ushort4 ov;
            ov.x = f2bf(o[0] * rl); ov.y = f2bf(o[1] * rl);
            ov.z = f2bf(o[2] * rl); ov.w = f2bf(o[3] * rl);
            *(ushort4*)(po + ((size_t)(cb * NH + h) * SEQN + t) * HD + dtm * 16 + quad * 4) = ov;
            if (ws == 0 && quad == 0 && j == 0)
                ml[(size_t)(cb * NH + h) * SEQN + t] = make_float2(0.f, lt[nt]);
        }
    }
}

// ---------------- merge s-chunks (weights = per-chunk l) -> attnoT [t][c] bf16
__global__ __launch_bounds__(256) void attn_merge(const unsigned short* __restrict__ po,
                                                  const float2* __restrict__ ml,
                                                  unsigned short* __restrict__ attnoT) {
    const int idx = blockIdx.x * 256 + threadIdx.x;
    const int t  = idx >> 7;
    const int c4 = (idx & 127) << 2;
    const int h  = c4 >> 6;
    const int d  = c4 & 63;

    float a0 = 0.f, a1 = 0.f, a2 = 0.f, a3 = 0.f, denom = 0.f;
#pragma unroll
    for (int cb = 0; cb < SC; cb++) {
        float wgt = ml[(size_t)(cb * NH + h) * SEQN + t].y;
        denom += wgt;
        ushort4 o = *(const ushort4*)(po + ((size_t)(cb * NH + h) * SEQN + t) * HD + d);
        a0 += wgt * bf2f(o.x);
        a1 += wgt * bf2f(o.y);
        a2 += wgt * bf2f(o.z);
        a3 += wgt * bf2f(o.w);
    }
    const float rd = 1.0f / denom;
    ushort4 r;
    r.x = f2bf(a0 * rd); r.y = f2bf(a1 * rd); r.z = f2bf(a2 * rd); r.w = f2bf(a3 * rd);
    *(ushort4*)(attnoT + (size_t)t * CCH + c4) = r;
}

extern "C" void kernel_launch(void* const* d_in, const int* in_sizes, int n_in,
                              void* d_out, int out_size, void* d_ws, size_t ws_size,
                              hipStream_t stream) {
    const float* x      = (const float*)d_in[0];
    const float* gn_w   = (const float*)d_in[1];
    const float* gn_b   = (const float*)d_in[2];
    const float* qkv_w  = (const float*)d_in[3];
    const float* qkv_b  = (const float*)d_in[4];
    const float* proj_w = (const float*)d_in[5];
    const float* proj_b = (const float*)d_in[6];
    float* out = (float*)d_out;

    char* ws = (char*)d_ws;
    float2* partials = (float2*)ws;                                // 2 KB
    unsigned short* xnT   = (unsigned short*)(ws + 2048);          // 4096*512
    unsigned short* wq_bf = xnT + (size_t)SEQN * CCH;              // 1536*512
    unsigned short* wp_bf = wq_bf + (size_t)3 * CCH * CCH;         // 512*512
    unsigned short* qt    = wp_bf + (size_t)CCH * CCH;             // 8*4096*64
    unsigned short* kt    = qt + (size_t)NH * SEQN * HD;
    unsigned short* vv    = kt + (size_t)NH * SEQN * HD;
    unsigned short* po    = vv + (size_t)NH * SEQN * HD;           // SC*8*4096*64
    unsigned short* attnoT = po + (size_t)SC * NH * SEQN * HD;     // 4096*512
    float2* ml = (float2*)(attnoT + (size_t)SEQN * CCH);           // SC*8*4096

    gn_stats<<<256, 256, 0, stream>>>(x, partials);
    gn_norm_t<<<dim3(SEQN / 64, CCH / 64), 256, 0, stream>>>(x, partials, gn_w, gn_b, xnT);
    cvt_w<<<(3 * CCH * CCH + CCH * CCH) / 4 / 256, 256, 0, stream>>>(qkv_w, proj_w, wq_bf, wp_bf);
    gemm_qkv<<<dim3(SEQN / 128, 3 * CCH / 128), 256, 0, stream>>>(wq_bf, xnT, qkv_b, qt, kt, vv);
    attn<<<dim3(SEQN / 64, SC, NH), 256, 0, stream>>>(qt, kt, vv, po, ml);
    attn_merge<<<SEQN * 128 / 256, 256, 0, stream>>>(po, ml, attnoT);
    gemm_proj<<<dim3(SEQN / 128, CCH / 64), 256, 0, stream>>>(wp_bf, attnoT, proj_b, x, out);
}